// Round 16
// baseline (1521.729 us; speedup 1.0000x reference)
//
#include <hip/hip_runtime.h>

#define NQ      3136
#define QPAD    3328
#define MM      65536
#define CC      768
#define NQB     13
#define KTILES  12              // BK64 tiles per qb

typedef int   i32x4v __attribute__((ext_vector_type(4)));
typedef int   i32x8v __attribute__((ext_vector_type(8)));
typedef float f32x16 __attribute__((ext_vector_type(16)));

union U8 { i32x8v v8; struct { i32x4v lo; i32x4v hi; } p; };

// pack 16 fp32 -> 16 fp8 e4m3 bytes (4 dwords)
__device__ __forceinline__ i32x4v pk16(float4 f0, float4 f1, float4 f2, float4 f3) {
  i32x4v w;
  int t;
  t = __builtin_amdgcn_cvt_pk_fp8_f32(f0.x, f0.y, 0, false);
  w[0] = __builtin_amdgcn_cvt_pk_fp8_f32(f0.z, f0.w, t, true);
  t = __builtin_amdgcn_cvt_pk_fp8_f32(f1.x, f1.y, 0, false);
  w[1] = __builtin_amdgcn_cvt_pk_fp8_f32(f1.z, f1.w, t, true);
  t = __builtin_amdgcn_cvt_pk_fp8_f32(f2.x, f2.y, 0, false);
  w[2] = __builtin_amdgcn_cvt_pk_fp8_f32(f2.z, f2.w, t, true);
  t = __builtin_amdgcn_cvt_pk_fp8_f32(f3.x, f3.y, 0, false);
  w[3] = __builtin_amdgcn_cvt_pk_fp8_f32(f3.z, f3.w, t, true);
  return w;
}

// ---------------- fused: fp32 -> fp8 e4m3 ROW-MAJOR + sumsq ----------
__global__ __launch_bounds__(256) void convert_bank_y2(const float* __restrict__ bank,
                                                       unsigned char* __restrict__ dst,
                                                       float* __restrict__ y2) {
  int row = blockIdx.x * 4 + (threadIdx.x >> 6);
  int lane = threadIdx.x & 63;
  float s = 0.f;
  i32x4v w;
  if (lane < 48) {
    const float* src = bank + (size_t)row * CC + lane * 16;
    float4 f0 = *reinterpret_cast<const float4*>(src);
    float4 f1 = *reinterpret_cast<const float4*>(src + 4);
    float4 f2 = *reinterpret_cast<const float4*>(src + 8);
    float4 f3 = *reinterpret_cast<const float4*>(src + 12);
    s = f0.x*f0.x + f0.y*f0.y + f0.z*f0.z + f0.w*f0.w
      + f1.x*f1.x + f1.y*f1.y + f1.z*f1.z + f1.w*f1.w
      + f2.x*f2.x + f2.y*f2.y + f2.z*f2.z + f2.w*f2.w
      + f3.x*f3.x + f3.y*f3.y + f3.z*f3.z + f3.w*f3.w;
    w = pk16(f0, f1, f2, f3);
  }
#pragma unroll
  for (int m = 32; m >= 1; m >>= 1) s += __shfl_xor(s, m, 64);
  if (lane == 0) y2[row] = s;
  if (lane < 48)
    *reinterpret_cast<i32x4v*>(dst + (size_t)row * CC + lane * 16) = w;
}

__global__ __launch_bounds__(256) void convert_tok_x2(const float* __restrict__ tok,
                                                      unsigned char* __restrict__ dst,
                                                      float* __restrict__ x2) {
  int row = blockIdx.x * 4 + (threadIdx.x >> 6);  // < QPAD
  int lane = threadIdx.x & 63;
  int rs = row < NQ ? row : NQ - 1;
  float s = 0.f;
  i32x4v w;
  if (lane < 48) {
    const float* src = tok + (size_t)rs * CC + lane * 16;
    float4 f0 = *reinterpret_cast<const float4*>(src);
    float4 f1 = *reinterpret_cast<const float4*>(src + 4);
    float4 f2 = *reinterpret_cast<const float4*>(src + 8);
    float4 f3 = *reinterpret_cast<const float4*>(src + 12);
    s = f0.x*f0.x + f0.y*f0.y + f0.z*f0.z + f0.w*f0.w
      + f1.x*f1.x + f1.y*f1.y + f1.z*f1.z + f1.w*f1.w
      + f2.x*f2.x + f2.y*f2.y + f2.z*f2.z + f2.w*f2.w
      + f3.x*f3.x + f3.y*f3.y + f3.z*f3.z + f3.w*f3.w;
    w = pk16(f0, f1, f2, f3);
  }
#pragma unroll
  for (int m = 32; m >= 1; m >>= 1) s += __shfl_xor(s, m, 64);
  if (lane == 0) x2[row] = s;
  if (lane < 48)
    *reinterpret_cast<i32x4v*>(dst + (size_t)row * CC + lane * 16) = w;
}

// ---------------- direct-to-register fp8 GEMM + per-query top-5 ----------------
// 256 blocks, block b = mtile. NO LDS staging, NO K-loop barriers: each wave
// global_load_dwordx4's its own fragments (row-major fp8), L1 serves the 4x/2x
// intra-CU reuse, register double-buffer, compiler-counted vmcnt. 12-kt loop
// fully unrolled so k-offsets are immediates.
__global__ __launch_bounds__(512, 2) void gemm_topk(
    const unsigned char* __restrict__ bf8, const unsigned char* __restrict__ tf8,
    const float* __restrict__ y2g, const float* __restrict__ x2g,
    unsigned* __restrict__ cand) {
  __shared__ float y2s[256];
  __shared__ unsigned fscratch[256 * 5];

  int b = blockIdx.x;
  int tid = threadIdx.x;
  int lane = tid & 63;
  int wid = tid >> 6;
  int wq = wid & 3;
  int wm = wid >> 2;
  int l31 = lane & 31;
  int lhi = lane >> 5;

  // constant per-lane byte offsets (A fixed all kernel; B advances per qb)
  const unsigned char* pA[4];
#pragma unroll
  for (int mi = 0; mi < 4; ++mi)
    pA[mi] = bf8 + (size_t)(b * 256 + wm * 128 + mi * 32 + l31) * CC + lhi * 32;
  const unsigned char* pB[2];
#pragma unroll
  for (int qj = 0; qj < 2; ++qj)
    pB[qj] = tf8 + (size_t)(wq * 64 + qj * 32 + l31) * CC + lhi * 32;

  float thrp[2];
  auto set_thr = [&](int qb) {
#pragma unroll
    for (int qj = 0; qj < 2; ++qj) {
      int qg = qb * 256 + wq * 64 + qj * 32 + l31;
      int qgc = qg < NQ ? qg : NQ - 1;
      float x2q = x2g[qgc];
      thrp[qj] = 768.f - 3.f * sqrtf(1536.f + 4.f * x2q);
    }
  };

  float lv[2][5];
  unsigned li[2][5];
#pragma unroll
  for (int qj = 0; qj < 2; ++qj)
#pragma unroll
    for (int s = 0; s < 5; ++s) { lv[qj][s] = 3.4e38f; li[qj][s] = 0u; }

  f32x16 acc[4][2];

  auto insert_pass = [&]() {
#pragma unroll
    for (int mi = 0; mi < 4; ++mi) {
#pragma unroll
      for (int r = 0; r < 16; ++r) {
        int mloc = wm * 128 + mi * 32 + (r & 3) + ((r >> 2) << 3) + (lhi << 2);
        float y2v = y2s[mloc];
#pragma unroll
        for (int qj = 0; qj < 2; ++qj) {
          float d2p = fmaf(-2.f, acc[mi][qj][r], y2v);
          if (d2p < thrp[qj] && d2p < lv[qj][4]) {
            float v = d2p;
            unsigned idv = (unsigned)mloc;
#pragma unroll
            for (int s = 0; s < 5; ++s) {
              bool less = v < lv[qj][s];
              float tv = lv[qj][s]; unsigned ti = li[qj][s];
              if (less) { lv[qj][s] = v; li[qj][s] = idv; v = tv; idv = ti; }
            }
          }
        }
      }
    }
  };

  auto flushq = [&](int qb) {
#pragma unroll
    for (int qj = 0; qj < 2; ++qj) {
      float ov[5];
      unsigned oi[5];
#pragma unroll
      for (int j = 0; j < 5; ++j) {
        ov[j] = __shfl_xor(lv[qj][j], 32, 64);
        oi[j] = (unsigned)__shfl_xor((int)li[qj][j], 32, 64);
      }
#pragma unroll
      for (int j = 0; j < 5; ++j) {
        float v = ov[j];
        unsigned idv = oi[j];
#pragma unroll
        for (int s = 0; s < 5; ++s) {
          bool less = v < lv[qj][s];
          float tv = lv[qj][s]; unsigned ti = li[qj][s];
          if (less) { lv[qj][s] = v; li[qj][s] = idv; v = tv; idv = ti; }
        }
      }
    }
    unsigned pk[2][5];
#pragma unroll
    for (int qj = 0; qj < 2; ++qj)
#pragma unroll
      for (int s = 0; s < 5; ++s)
        pk[qj][s] = (lv[qj][s] >= 3.0e38f) ? 0xFFFFFFFFu
                    : ((__float_as_uint(fmaxf(lv[qj][s], 0.f)) & 0xFFFFFF00u) | li[qj][s]);
    if (wm == 1 && lhi == 0) {
#pragma unroll
      for (int qj = 0; qj < 2; ++qj) {
        int ql = wq * 64 + qj * 32 + l31;
#pragma unroll
        for (int s = 0; s < 5; ++s) fscratch[ql * 5 + s] = pk[qj][s];
      }
    }
    __syncthreads();
    if (wm == 0 && lhi == 0) {
#pragma unroll
      for (int qj = 0; qj < 2; ++qj) {
        int ql = wq * 64 + qj * 32 + l31;
#pragma unroll
        for (int j = 0; j < 5; ++j) {
          unsigned v = fscratch[ql * 5 + j];
#pragma unroll
          for (int s = 0; s < 5; ++s) {
            unsigned tv = pk[qj][s];
            bool less = v < tv;
            if (less) { pk[qj][s] = v; v = tv; }
          }
        }
        size_t qg = (size_t)(qb * 256 + ql);
        unsigned* cp = cand + (qg * 256 + b) * 5;
#pragma unroll
        for (int s = 0; s < 5; ++s) cp[s] = pk[qj][s];
      }
    }
    __syncthreads();   // fscratch reusable next qb
#pragma unroll
    for (int qj = 0; qj < 2; ++qj)
#pragma unroll
      for (int s = 0; s < 5; ++s) { lv[qj][s] = 3.4e38f; li[qj][s] = 0u; }
  };

  if (tid < 256) y2s[tid] = y2g[b * 256 + tid];
  set_thr(0);
  __syncthreads();

  U8 opA[2][4], opB[2][2];

  for (int qb = 0; qb < NQB; ++qb) {
    // prologue: load kt=0 into set 0
#pragma unroll
    for (int mi = 0; mi < 4; ++mi) {
      opA[0][mi].p.lo = *reinterpret_cast<const i32x4v*>(pA[mi]);
      opA[0][mi].p.hi = *reinterpret_cast<const i32x4v*>(pA[mi] + 16);
    }
#pragma unroll
    for (int qj = 0; qj < 2; ++qj) {
      opB[0][qj].p.lo = *reinterpret_cast<const i32x4v*>(pB[qj]);
      opB[0][qj].p.hi = *reinterpret_cast<const i32x4v*>(pB[qj] + 16);
    }
#pragma unroll
    for (int kt = 0; kt < KTILES; ++kt) {
      const int cur = kt & 1, nxt = cur ^ 1;
      if (kt + 1 < KTILES) {
        const int o = (kt + 1) * 64;
#pragma unroll
        for (int mi = 0; mi < 4; ++mi) {
          opA[nxt][mi].p.lo = *reinterpret_cast<const i32x4v*>(pA[mi] + o);
          opA[nxt][mi].p.hi = *reinterpret_cast<const i32x4v*>(pA[mi] + o + 16);
        }
#pragma unroll
        for (int qj = 0; qj < 2; ++qj) {
          opB[nxt][qj].p.lo = *reinterpret_cast<const i32x4v*>(pB[qj] + o);
          opB[nxt][qj].p.hi = *reinterpret_cast<const i32x4v*>(pB[qj] + o + 16);
        }
      }
      __builtin_amdgcn_s_setprio(1);
      if (kt == 0) {
        f32x16 z;
#pragma unroll
        for (int e = 0; e < 16; ++e) z[e] = 0.f;
#pragma unroll
        for (int mi = 0; mi < 4; ++mi) {
          acc[mi][0] = __builtin_amdgcn_mfma_scale_f32_32x32x64_f8f6f4(
              opA[cur][mi].v8, opB[cur][0].v8, z, 0, 0, 0, 0x7F7F7F7F, 0, 0x7F7F7F7F);
          acc[mi][1] = __builtin_amdgcn_mfma_scale_f32_32x32x64_f8f6f4(
              opA[cur][mi].v8, opB[cur][1].v8, z, 0, 0, 0, 0x7F7F7F7F, 0, 0x7F7F7F7F);
        }
      } else {
#pragma unroll
        for (int mi = 0; mi < 4; ++mi) {
          acc[mi][0] = __builtin_amdgcn_mfma_scale_f32_32x32x64_f8f6f4(
              opA[cur][mi].v8, opB[cur][0].v8, acc[mi][0], 0, 0, 0, 0x7F7F7F7F, 0, 0x7F7F7F7F);
          acc[mi][1] = __builtin_amdgcn_mfma_scale_f32_32x32x64_f8f6f4(
              opA[cur][mi].v8, opB[cur][1].v8, acc[mi][1], 0, 0, 0, 0x7F7F7F7F, 0, 0x7F7F7F7F);
        }
      }
      __builtin_amdgcn_s_setprio(0);
    }
    insert_pass();
    flushq(qb);
    if (qb + 1 < NQB) {
      set_thr(qb + 1);
#pragma unroll
      for (int qj = 0; qj < 2; ++qj) pB[qj] += 256 * CC;
    }
  }
}

// ---------------- fallback (no workspace): fp32 VALU-convert + LDS, bf16-free ----
__global__ __launch_bounds__(512, 2) void gemm_topk_fb(
    const float* __restrict__ tok, const float* __restrict__ bank,
    const float* __restrict__ y2g, const float* __restrict__ x2g,
    unsigned* __restrict__ cand) {
  __shared__ __align__(16) char sA[16384];
  __shared__ __align__(16) char sB[16384];
  __shared__ float y2s[256];
  __shared__ unsigned fscratch[256 * 5];

  int b = blockIdx.x;
  int tid = threadIdx.x;
  int lane = tid & 63;
  int wid = tid >> 6;
  int wq = wid & 3;
  int wm = wid >> 2;
  int l31 = lane & 31;
  int lhi = lane >> 5;

  int offA[4], offB[2];
#pragma unroll
  for (int mi = 0; mi < 4; ++mi)
    offA[mi] = (wm * 128 + mi * 32 + l31) * 64 + lhi * 32;
#pragma unroll
  for (int qj = 0; qj < 2; ++qj)
    offB[qj] = (wq * 64 + qj * 32 + l31) * 64 + lhi * 32;

  float thrp[2];
  auto set_thr = [&](int qb) {
#pragma unroll
    for (int qj = 0; qj < 2; ++qj) {
      int qg = qb * 256 + wq * 64 + qj * 32 + l31;
      int qgc = qg < NQ ? qg : NQ - 1;
      float x2q = x2g[qgc];
      thrp[qj] = 768.f - 3.f * sqrtf(1536.f + 4.f * x2q);
    }
  };

  float lv[2][5];
  unsigned li[2][5];
#pragma unroll
  for (int qj = 0; qj < 2; ++qj)
#pragma unroll
    for (int s = 0; s < 5; ++s) { lv[qj][s] = 3.4e38f; li[qj][s] = 0u; }

  f32x16 acc[4][2];

  if (tid < 256) y2s[tid] = y2g[b * 256 + tid];
  set_thr(0);

  for (int qb = 0; qb < NQB; ++qb) {
    for (int kt = 0; kt < KTILES; ++kt) {
      __syncthreads();
#pragma unroll
      for (int j = 0; j < 2; ++j) {
        int u = tid * 2 + j;
        int row = u >> 2, s = u & 3;
        const float* srcA = bank + (size_t)(b * 256 + row) * CC + kt * 64 + s * 16;
        float4 f0 = *reinterpret_cast<const float4*>(srcA);
        float4 f1 = *reinterpret_cast<const float4*>(srcA + 4);
        float4 f2 = *reinterpret_cast<const float4*>(srcA + 8);
        float4 f3 = *reinterpret_cast<const float4*>(srcA + 12);
        *reinterpret_cast<i32x4v*>(&sA[row * 64 + s * 16]) = pk16(f0, f1, f2, f3);
        int qr = qb * 256 + row;
        qr = qr < NQ ? qr : NQ - 1;
        const float* srcB = tok + (size_t)qr * CC + kt * 64 + s * 16;
        f0 = *reinterpret_cast<const float4*>(srcB);
        f1 = *reinterpret_cast<const float4*>(srcB + 4);
        f2 = *reinterpret_cast<const float4*>(srcB + 8);
        f3 = *reinterpret_cast<const float4*>(srcB + 12);
        *reinterpret_cast<i32x4v*>(&sB[row * 64 + s * 16]) = pk16(f0, f1, f2, f3);
      }
      __syncthreads();
      U8 aV[4], bV[2];
#pragma unroll
      for (int qj = 0; qj < 2; ++qj) {
        bV[qj].p.lo = *reinterpret_cast<const i32x4v*>(&sB[offB[qj]]);
        bV[qj].p.hi = *reinterpret_cast<const i32x4v*>(&sB[offB[qj] + 16]);
      }
#pragma unroll
      for (int mi = 0; mi < 4; ++mi) {
        aV[mi].p.lo = *reinterpret_cast<const i32x4v*>(&sA[offA[mi]]);
        aV[mi].p.hi = *reinterpret_cast<const i32x4v*>(&sA[offA[mi] + 16]);
      }
      if (kt == 0) {
        f32x16 z;
#pragma unroll
        for (int e = 0; e < 16; ++e) z[e] = 0.f;
#pragma unroll
        for (int mi = 0; mi < 4; ++mi) {
          acc[mi][0] = __builtin_amdgcn_mfma_scale_f32_32x32x64_f8f6f4(
              aV[mi].v8, bV[0].v8, z, 0, 0, 0, 0x7F7F7F7F, 0, 0x7F7F7F7F);
          acc[mi][1] = __builtin_amdgcn_mfma_scale_f32_32x32x64_f8f6f4(
              aV[mi].v8, bV[1].v8, z, 0, 0, 0, 0x7F7F7F7F, 0, 0x7F7F7F7F);
        }
      } else {
#pragma unroll
        for (int mi = 0; mi < 4; ++mi) {
          acc[mi][0] = __builtin_amdgcn_mfma_scale_f32_32x32x64_f8f6f4(
              aV[mi].v8, bV[0].v8, acc[mi][0], 0, 0, 0, 0x7F7F7F7F, 0, 0x7F7F7F7F);
          acc[mi][1] = __builtin_amdgcn_mfma_scale_f32_32x32x64_f8f6f4(
              aV[mi].v8, bV[1].v8, acc[mi][1], 0, 0, 0, 0x7F7F7F7F, 0, 0x7F7F7F7F);
        }
      }
    }
    __syncthreads();
    // insert + flush (same as main)
#pragma unroll
    for (int mi = 0; mi < 4; ++mi) {
#pragma unroll
      for (int r = 0; r < 16; ++r) {
        int mloc = wm * 128 + mi * 32 + (r & 3) + ((r >> 2) << 3) + (lhi << 2);
        float y2v = y2s[mloc];
#pragma unroll
        for (int qj = 0; qj < 2; ++qj) {
          float d2p = fmaf(-2.f, acc[mi][qj][r], y2v);
          if (d2p < thrp[qj] && d2p < lv[qj][4]) {
            float v = d2p;
            unsigned idv = (unsigned)mloc;
#pragma unroll
            for (int s = 0; s < 5; ++s) {
              bool less = v < lv[qj][s];
              float tv = lv[qj][s]; unsigned ti = li[qj][s];
              if (less) { lv[qj][s] = v; li[qj][s] = idv; v = tv; idv = ti; }
            }
          }
        }
      }
    }
#pragma unroll
    for (int qj = 0; qj < 2; ++qj) {
      float ov[5];
      unsigned oi[5];
#pragma unroll
      for (int j = 0; j < 5; ++j) {
        ov[j] = __shfl_xor(lv[qj][j], 32, 64);
        oi[j] = (unsigned)__shfl_xor((int)li[qj][j], 32, 64);
      }
#pragma unroll
      for (int j = 0; j < 5; ++j) {
        float v = ov[j];
        unsigned idv = oi[j];
#pragma unroll
        for (int s = 0; s < 5; ++s) {
          bool less = v < lv[qj][s];
          float tv = lv[qj][s]; unsigned ti = li[qj][s];
          if (less) { lv[qj][s] = v; li[qj][s] = idv; v = tv; idv = ti; }
        }
      }
    }
    unsigned pk[2][5];
#pragma unroll
    for (int qj = 0; qj < 2; ++qj)
#pragma unroll
      for (int s = 0; s < 5; ++s)
        pk[qj][s] = (lv[qj][s] >= 3.0e38f) ? 0xFFFFFFFFu
                    : ((__float_as_uint(fmaxf(lv[qj][s], 0.f)) & 0xFFFFFF00u) | li[qj][s]);
    if (wm == 1 && lhi == 0) {
#pragma unroll
      for (int qj = 0; qj < 2; ++qj) {
        int ql = wq * 64 + qj * 32 + l31;
#pragma unroll
        for (int s = 0; s < 5; ++s) fscratch[ql * 5 + s] = pk[qj][s];
      }
    }
    __syncthreads();
    if (wm == 0 && lhi == 0) {
#pragma unroll
      for (int qj = 0; qj < 2; ++qj) {
        int ql = wq * 64 + qj * 32 + l31;
#pragma unroll
        for (int j = 0; j < 5; ++j) {
          unsigned v = fscratch[ql * 5 + j];
#pragma unroll
          for (int s = 0; s < 5; ++s) {
            unsigned tv = pk[qj][s];
            bool less = v < tv;
            if (less) { pk[qj][s] = v; v = tv; }
          }
        }
        size_t qg = (size_t)(qb * 256 + ql);
        unsigned* cp = cand + (qg * 256 + b) * 5;
#pragma unroll
        for (int s = 0; s < 5; ++s) cp[s] = pk[qj][s];
      }
    }
    __syncthreads();
#pragma unroll
    for (int qj = 0; qj < 2; ++qj)
#pragma unroll
      for (int s = 0; s < 5; ++s) { lv[qj][s] = 3.4e38f; li[qj][s] = 0u; }
    if (qb + 1 < NQB) set_thr(qb + 1);
  }
}

// ---------------- merge (r14 version): wave/query, top-16 + exact rescore ----
__global__ __launch_bounds__(256) void merge_rescore(
    const float* __restrict__ tok, const float* __restrict__ bank,
    const unsigned* __restrict__ cand, float* __restrict__ out) {
  int q = blockIdx.x * 4 + (threadIdx.x >> 6);
  int lane = threadIdx.x & 63;
  const unsigned* cp = cand + (size_t)q * 1280;
  unsigned e[20];
#pragma unroll
  for (int j = 0; j < 20; ++j) e[j] = cp[lane * 20 + j];
  unsigned gids[16];
#pragma unroll
  for (int r = 0; r < 16; ++r) {
    unsigned bv = e[0];
#pragma unroll
    for (int j = 1; j < 20; ++j) bv = e[j] < bv ? e[j] : bv;
    unsigned rv = bv;
    int rl = lane;
#pragma unroll
    for (int m = 32; m >= 1; m >>= 1) {
      unsigned ov = (unsigned)__shfl_xor((int)rv, m, 64);
      int ol = __shfl_xor(rl, m, 64);
      if (ov < rv || (ov == rv && ol < rl)) { rv = ov; rl = ol; }
    }
    unsigned gid = 0;
    if (lane == rl) {
      bool done = false;
#pragma unroll
      for (int j = 0; j < 20; ++j) {
        if (!done && e[j] == rv) {
          gid = (unsigned)((lane * 4 + j / 5) * 256) + (e[j] & 255u);
          e[j] = 0xFFFFFFFFu;
          done = true;
        }
      }
    }
    gids[r] = (unsigned)__shfl((int)gid, rl, 64);
  }
  float xv[12];
  {
    const float* xp = tok + (size_t)q * CC + lane * 12;
    float4 a = *reinterpret_cast<const float4*>(xp);
    float4 bq = *reinterpret_cast<const float4*>(xp + 4);
    float4 cc4 = *reinterpret_cast<const float4*>(xp + 8);
    xv[0] = a.x; xv[1] = a.y; xv[2] = a.z; xv[3] = a.w;
    xv[4] = bq.x; xv[5] = bq.y; xv[6] = bq.z; xv[7] = bq.w;
    xv[8] = cc4.x; xv[9] = cc4.y; xv[10] = cc4.z; xv[11] = cc4.w;
  }
  float d2e[16];
#pragma unroll
  for (int r = 0; r < 16; ++r) {
    const float* yp = bank + (size_t)(gids[r] & (MM - 1)) * CC + lane * 12;
    float4 a = *reinterpret_cast<const float4*>(yp);
    float4 bq = *reinterpret_cast<const float4*>(yp + 4);
    float4 cc4 = *reinterpret_cast<const float4*>(yp + 8);
    float yv[12];
    yv[0] = a.x; yv[1] = a.y; yv[2] = a.z; yv[3] = a.w;
    yv[4] = bq.x; yv[5] = bq.y; yv[6] = bq.z; yv[7] = bq.w;
    yv[8] = cc4.x; yv[9] = cc4.y; yv[10] = cc4.z; yv[11] = cc4.w;
    float s = 0.f;
#pragma unroll
    for (int e2 = 0; e2 < 12; ++e2) {
      float d = xv[e2] - yv[e2];
      s = fmaf(d, d, s);
    }
#pragma unroll
    for (int m = 32; m >= 1; m >>= 1) s += __shfl_xor(s, m, 64);
    d2e[r] = s;
  }
  float d1sq = 0.f, d5sq = 0.f;
#pragma unroll
  for (int r5 = 0; r5 < 5; ++r5) {
    float bv = d2e[0];
    int bj = 0;
#pragma unroll
    for (int j = 1; j < 16; ++j)
      if (d2e[j] < bv) { bv = d2e[j]; bj = j; }
    if (r5 == 0) d1sq = bv;
    if (r5 == 4) d5sq = bv;
#pragma unroll
    for (int j = 0; j < 16; ++j)
      if (j == bj) d2e[j] = 3.4e38f;
  }
  float d1 = sqrtf(fmaxf(d1sq, 0.f));
  float d5 = sqrtf(fmaxf(d5sq, 0.f));
  float gap = fmaxf(d5 - d1, 0.f);
  float sc = d1 * (1.f - expf(-gap));
  if (lane == 0) out[q] = sc;
}

// ---------------- prep (fallback path only) ----------------
__global__ __launch_bounds__(256) void prep_sumsq(const float* __restrict__ tok,
                                                  const float* __restrict__ bank,
                                                  float* __restrict__ y2,
                                                  float* __restrict__ x2) {
  int row = blockIdx.x * 4 + (threadIdx.x >> 6);
  int lane = threadIdx.x & 63;
  const float* src;
  float* dst;
  bool zero = false;
  if (row < MM) {
    src = bank + (size_t)row * CC;
    dst = y2 + row;
  } else {
    int rx = row - MM;
    if (rx >= QPAD) return;
    zero = (rx >= NQ);
    src = tok + (size_t)(zero ? 0 : rx) * CC;
    dst = x2 + rx;
  }
  float s = 0.f;
#pragma unroll
  for (int p = 0; p < 3; ++p) {
    float4 v = *reinterpret_cast<const float4*>(src + (lane + p * 64) * 4);
    s += v.x * v.x + v.y * v.y + v.z * v.z + v.w * v.w;
  }
#pragma unroll
  for (int m = 32; m >= 1; m >>= 1) s += __shfl_xor(s, m, 64);
  if (lane == 0) *dst = zero ? 0.f : s;
}

extern "C" void kernel_launch(void* const* d_in, const int* in_sizes, int n_in,
                              void* d_out, int out_size, void* d_ws, size_t ws_size,
                              hipStream_t stream) {
  const float* tok = (const float*)d_in[0];   // 3136x768 fp32
  const float* bank = (const float*)d_in[1];  // 65536x768 fp32
  float* out = (float*)d_out;                 // 3136 fp32
  char* ws = (char*)d_ws;
  float* y2 = (float*)ws;                                     // 256KB
  float* x2 = (float*)(ws + 262144);                          // 13KB
  unsigned* cand = (unsigned*)(ws + 1048576);                 // 17.04MB
  unsigned char* bf8 = (unsigned char*)(ws + 18874368);       // 50.33MB row-major fp8
  unsigned char* tf8 = (unsigned char*)(ws + 69206016);       // 2.56MB row-major fp8
  const size_t WS_NEED = 71761920ull;

  if (ws_size >= WS_NEED) {
    convert_bank_y2<<<MM / 4, 256, 0, stream>>>(bank, bf8, y2);
    convert_tok_x2<<<QPAD / 4, 256, 0, stream>>>(tok, tf8, x2);
    gemm_topk<<<256, 512, 0, stream>>>(bf8, tf8, y2, x2, cand);
  } else {
    prep_sumsq<<<(MM + QPAD) / 4, 256, 0, stream>>>(tok, bank, y2, x2);
    gemm_topk_fb<<<256, 512, 0, stream>>>(tok, bank, y2, x2, cand);
  }
  merge_rescore<<<NQ / 4, 256, 0, stream>>>(tok, bank, cand, out);
}

// Round 17
// 338.264 us; speedup vs baseline: 4.4986x; 4.4986x over previous
//
#include <hip/hip_runtime.h>

#define NQ      3136
#define QPAD    3328
#define MM      65536
#define CC      768
#define NQB     13
#define KTILES  12              // BK64 tiles per qb
#define TT      (NQB * KTILES)  // 156

typedef int   i32x4v __attribute__((ext_vector_type(4)));
typedef int   i32x8v __attribute__((ext_vector_type(8)));
typedef float f32x16 __attribute__((ext_vector_type(16)));

union U8 { i32x8v v8; struct { i32x4v lo; i32x4v hi; } p; };

#define GLOAD16(gp, lp) __builtin_amdgcn_global_load_lds( \
    (const __attribute__((address_space(1))) void*)(gp), \
    (__attribute__((address_space(3))) void*)(lp), 16, 0, 0)

// 4-slot swizzle (r7+: measured 0 bank conflicts)
__device__ __forceinline__ int swz4(int s, int row) {
  return s ^ ((row ^ (row >> 2)) & 3);
}

// pack 16 fp32 -> 16 fp8 e4m3 bytes (4 dwords)
__device__ __forceinline__ i32x4v pk16(float4 f0, float4 f1, float4 f2, float4 f3) {
  i32x4v w;
  int t;
  t = __builtin_amdgcn_cvt_pk_fp8_f32(f0.x, f0.y, 0, false);
  w[0] = __builtin_amdgcn_cvt_pk_fp8_f32(f0.z, f0.w, t, true);
  t = __builtin_amdgcn_cvt_pk_fp8_f32(f1.x, f1.y, 0, false);
  w[1] = __builtin_amdgcn_cvt_pk_fp8_f32(f1.z, f1.w, t, true);
  t = __builtin_amdgcn_cvt_pk_fp8_f32(f2.x, f2.y, 0, false);
  w[2] = __builtin_amdgcn_cvt_pk_fp8_f32(f2.z, f2.w, t, true);
  t = __builtin_amdgcn_cvt_pk_fp8_f32(f3.x, f3.y, 0, false);
  w[3] = __builtin_amdgcn_cvt_pk_fp8_f32(f3.z, f3.w, t, true);
  return w;
}

// ---------------- prep (fallback path only) ----------------
__global__ __launch_bounds__(256) void prep_sumsq(const float* __restrict__ tok,
                                                  const float* __restrict__ bank,
                                                  float* __restrict__ y2,
                                                  float* __restrict__ x2) {
  int row = blockIdx.x * 4 + (threadIdx.x >> 6);
  int lane = threadIdx.x & 63;
  const float* src;
  float* dst;
  bool zero = false;
  if (row < MM) {
    src = bank + (size_t)row * CC;
    dst = y2 + row;
  } else {
    int rx = row - MM;
    if (rx >= QPAD) return;
    zero = (rx >= NQ);
    src = tok + (size_t)(zero ? 0 : rx) * CC;
    dst = x2 + rx;
  }
  float s = 0.f;
#pragma unroll
  for (int p = 0; p < 3; ++p) {
    float4 v = *reinterpret_cast<const float4*>(src + (lane + p * 64) * 4);
    s += v.x * v.x + v.y * v.y + v.z * v.z + v.w * v.w;
  }
#pragma unroll
  for (int m = 32; m >= 1; m >>= 1) s += __shfl_xor(s, m, 64);
  if (lane == 0) *dst = zero ? 0.f : s;
}

// ---------------- fused: fp32 -> fp8 e4m3 (tile-major pre-swizzled) + sumsq ----------
__global__ __launch_bounds__(256) void convert_bank_y2(const float* __restrict__ bank,
                                                       unsigned char* __restrict__ dst,
                                                       float* __restrict__ y2) {
  int row = blockIdx.x * 4 + (threadIdx.x >> 6);
  int lane = threadIdx.x & 63;
  float s = 0.f;
  i32x4v w;
  if (lane < 48) {
    const float* src = bank + (size_t)row * CC + lane * 16;
    float4 f0 = *reinterpret_cast<const float4*>(src);
    float4 f1 = *reinterpret_cast<const float4*>(src + 4);
    float4 f2 = *reinterpret_cast<const float4*>(src + 8);
    float4 f3 = *reinterpret_cast<const float4*>(src + 12);
    s = f0.x*f0.x + f0.y*f0.y + f0.z*f0.z + f0.w*f0.w
      + f1.x*f1.x + f1.y*f1.y + f1.z*f1.z + f1.w*f1.w
      + f2.x*f2.x + f2.y*f2.y + f2.z*f2.z + f2.w*f2.w
      + f3.x*f3.x + f3.y*f3.y + f3.z*f3.z + f3.w*f3.w;
    w = pk16(f0, f1, f2, f3);
  }
#pragma unroll
  for (int m = 32; m >= 1; m >>= 1) s += __shfl_xor(s, m, 64);
  if (lane == 0) y2[row] = s;
  if (lane < 48) {
    unsigned kt = lane >> 2, sl = lane & 3;
    unsigned tile = (unsigned)(row >> 8) * 12 + kt;
    unsigned r8 = row & 255;
    *reinterpret_cast<i32x4v*>(dst + ((size_t)tile << 14) + r8 * 64 + swz4(sl, r8) * 16) = w;
  }
}

__global__ __launch_bounds__(256) void convert_tok_x2(const float* __restrict__ tok,
                                                      unsigned char* __restrict__ dst,
                                                      float* __restrict__ x2) {
  int row = blockIdx.x * 4 + (threadIdx.x >> 6);  // < QPAD
  int lane = threadIdx.x & 63;
  int rs = row < NQ ? row : NQ - 1;
  float s = 0.f;
  i32x4v w;
  if (lane < 48) {
    const float* src = tok + (size_t)rs * CC + lane * 16;
    float4 f0 = *reinterpret_cast<const float4*>(src);
    float4 f1 = *reinterpret_cast<const float4*>(src + 4);
    float4 f2 = *reinterpret_cast<const float4*>(src + 8);
    float4 f3 = *reinterpret_cast<const float4*>(src + 12);
    s = f0.x*f0.x + f0.y*f0.y + f0.z*f0.z + f0.w*f0.w
      + f1.x*f1.x + f1.y*f1.y + f1.z*f1.z + f1.w*f1.w
      + f2.x*f2.x + f2.y*f2.y + f2.z*f2.z + f2.w*f2.w
      + f3.x*f3.x + f3.y*f3.y + f3.z*f3.z + f3.w*f3.w;
    w = pk16(f0, f1, f2, f3);
  }
#pragma unroll
  for (int m = 32; m >= 1; m >>= 1) s += __shfl_xor(s, m, 64);
  if (lane == 0) x2[row] = s;
  if (lane < 48) {
    unsigned kt = lane >> 2, sl = lane & 3;
    unsigned tile = (unsigned)(row >> 8) * 12 + kt;
    unsigned r8 = row & 255;
    *reinterpret_cast<i32x4v*>(dst + ((size_t)tile << 14) + r8 * 64 + swz4(sl, r8) * 16) = w;
  }
}

// ---------------- fused distance-GEMM (fp8) + per-query top-5 ----------------
// 256 blocks, block b = mtile. 4-slot LDS ring, 2-tile windows (1 barrier +
// 1 vmcnt(0) per 2 tiles), incremental scalar staging addresses, read-only
// insert_pass (acc re-init via first-tile C=0), fp8 mfma_scale 32x32x64.
template <int PRE>
__global__ __launch_bounds__(512, 2) void gemm_topk(
    const float* __restrict__ tok, const float* __restrict__ bank,
    const unsigned char* __restrict__ bf8, const unsigned char* __restrict__ tf8,
    const float* __restrict__ y2g, const float* __restrict__ x2g,
    unsigned* __restrict__ cand) {
  __shared__ __align__(16) char sA[4][16384];
  __shared__ __align__(16) char sB[4][16384];
  __shared__ float y2s[256];
  __shared__ unsigned fscratch[256 * 5];

  int b = blockIdx.x;          // == mtile
  int tid = threadIdx.x;
  int lane = tid & 63;
  int wid = tid >> 6;
  int wq = wid & 3;
  int wm = wid >> 2;
  int l31 = lane & 31;
  int lhi = lane >> 5;

  int offA[4][2], offB[2][2];
#pragma unroll
  for (int mi = 0; mi < 4; ++mi)
#pragma unroll
    for (int j = 0; j < 2; ++j) {
      int row = wm * 128 + mi * 32 + l31;
      offA[mi][j] = row * 64 + swz4(lhi * 2 + j, row) * 16;
    }
#pragma unroll
  for (int qj = 0; qj < 2; ++qj)
#pragma unroll
    for (int j = 0; j < 2; ++j) {
      int row = wq * 64 + qj * 32 + l31;
      offB[qj][j] = row * 64 + swz4(lhi * 2 + j, row) * 16;
    }

  float thrp[2];
  auto set_thr = [&](int qb) {
#pragma unroll
    for (int qj = 0; qj < 2; ++qj) {
      int qg = qb * 256 + wq * 64 + qj * 32 + l31;
      int qgc = qg < NQ ? qg : NQ - 1;
      float x2q = x2g[qgc];
      thrp[qj] = 768.f - 3.f * sqrtf(1536.f + 4.f * x2q);
    }
  };

  float lv[2][5];
  unsigned li[2][5];
#pragma unroll
  for (int qj = 0; qj < 2; ++qj)
#pragma unroll
    for (int s = 0; s < 5; ++s) { lv[qj][s] = 3.4e38f; li[qj][s] = 0u; }

  f32x16 acc[4][2];

  auto insert_pass = [&]() {   // read-only: acc re-init comes from first-tile C=0
#pragma unroll
    for (int mi = 0; mi < 4; ++mi) {
#pragma unroll
      for (int r = 0; r < 16; ++r) {
        int mloc = wm * 128 + mi * 32 + (r & 3) + ((r >> 2) << 3) + (lhi << 2);
        float y2v = y2s[mloc];
#pragma unroll
        for (int qj = 0; qj < 2; ++qj) {
          float d2p = fmaf(-2.f, acc[mi][qj][r], y2v);
          if (d2p < thrp[qj] && d2p < lv[qj][4]) {
            float v = d2p;
            unsigned idv = (unsigned)mloc;
#pragma unroll
            for (int s = 0; s < 5; ++s) {
              bool less = v < lv[qj][s];
              float tv = lv[qj][s]; unsigned ti = li[qj][s];
              if (less) { lv[qj][s] = v; li[qj][s] = idv; v = tv; idv = ti; }
            }
          }
        }
      }
    }
  };

  auto flushq = [&](int qb) {
#pragma unroll
    for (int qj = 0; qj < 2; ++qj) {
      float ov[5];
      unsigned oi[5];
#pragma unroll
      for (int j = 0; j < 5; ++j) {
        ov[j] = __shfl_xor(lv[qj][j], 32, 64);
        oi[j] = (unsigned)__shfl_xor((int)li[qj][j], 32, 64);
      }
#pragma unroll
      for (int j = 0; j < 5; ++j) {
        float v = ov[j];
        unsigned idv = oi[j];
#pragma unroll
        for (int s = 0; s < 5; ++s) {
          bool less = v < lv[qj][s];
          float tv = lv[qj][s]; unsigned ti = li[qj][s];
          if (less) { lv[qj][s] = v; li[qj][s] = idv; v = tv; idv = ti; }
        }
      }
    }
    unsigned pk[2][5];
#pragma unroll
    for (int qj = 0; qj < 2; ++qj)
#pragma unroll
      for (int s = 0; s < 5; ++s)
        pk[qj][s] = (lv[qj][s] >= 3.0e38f) ? 0xFFFFFFFFu
                    : ((__float_as_uint(fmaxf(lv[qj][s], 0.f)) & 0xFFFFFF00u) | li[qj][s]);
    if (wm == 1 && lhi == 0) {
#pragma unroll
      for (int qj = 0; qj < 2; ++qj) {
        int ql = wq * 64 + qj * 32 + l31;
#pragma unroll
        for (int s = 0; s < 5; ++s) fscratch[ql * 5 + s] = pk[qj][s];
      }
    }
    __syncthreads();
    if (wm == 0 && lhi == 0) {
#pragma unroll
      for (int qj = 0; qj < 2; ++qj) {
        int ql = wq * 64 + qj * 32 + l31;
#pragma unroll
        for (int j = 0; j < 5; ++j) {
          unsigned v = fscratch[ql * 5 + j];
#pragma unroll
          for (int s = 0; s < 5; ++s) {
            unsigned tv = pk[qj][s];
            bool less = v < tv;
            if (less) { pk[qj][s] = v; v = tv; }
          }
        }
        size_t qg = (size_t)(qb * 256 + ql);
        unsigned* cp = cand + (qg * 256 + b) * 5;
#pragma unroll
        for (int s = 0; s < 5; ++s) cp[s] = pk[qj][s];
      }
    }
#pragma unroll
    for (int qj = 0; qj < 2; ++qj)
#pragma unroll
      for (int s = 0; s < 5; ++s) { lv[qj][s] = 3.4e38f; li[qj][s] = 0u; }
  };

  auto do_mfma = [&](int u, bool first) {
    U8 aV[4], bV[2];
#pragma unroll
    for (int qj = 0; qj < 2; ++qj) {
      bV[qj].p.lo = *reinterpret_cast<const i32x4v*>(&sB[u][offB[qj][0]]);
      bV[qj].p.hi = *reinterpret_cast<const i32x4v*>(&sB[u][offB[qj][1]]);
    }
#pragma unroll
    for (int mi = 0; mi < 4; ++mi) {
      aV[mi].p.lo = *reinterpret_cast<const i32x4v*>(&sA[u][offA[mi][0]]);
      aV[mi].p.hi = *reinterpret_cast<const i32x4v*>(&sA[u][offA[mi][1]]);
    }
    __builtin_amdgcn_s_setprio(1);
    if (first) {
      f32x16 z;
#pragma unroll
      for (int e = 0; e < 16; ++e) z[e] = 0.f;
#pragma unroll
      for (int mi = 0; mi < 4; ++mi) {
        acc[mi][0] = __builtin_amdgcn_mfma_scale_f32_32x32x64_f8f6f4(
            aV[mi].v8, bV[0].v8, z, 0, 0, 0, 0x7F7F7F7F, 0, 0x7F7F7F7F);
        acc[mi][1] = __builtin_amdgcn_mfma_scale_f32_32x32x64_f8f6f4(
            aV[mi].v8, bV[1].v8, z, 0, 0, 0, 0x7F7F7F7F, 0, 0x7F7F7F7F);
      }
    } else {
#pragma unroll
      for (int mi = 0; mi < 4; ++mi) {
        acc[mi][0] = __builtin_amdgcn_mfma_scale_f32_32x32x64_f8f6f4(
            aV[mi].v8, bV[0].v8, acc[mi][0], 0, 0, 0, 0x7F7F7F7F, 0, 0x7F7F7F7F);
        acc[mi][1] = __builtin_amdgcn_mfma_scale_f32_32x32x64_f8f6f4(
            aV[mi].v8, bV[1].v8, acc[mi][1], 0, 0, 0, 0x7F7F7F7F, 0, 0x7F7F7F7F);
      }
    }
    __builtin_amdgcn_s_setprio(0);
  };

  if (tid < 256) y2s[tid] = y2g[b * 256 + tid];
  set_thr(0);

  if constexpr (PRE) {
    const size_t aBase = (size_t)b * (KTILES << 14);
    int t2v = 0, kt2 = 0;
    size_t bOff = 0;
    int vo = tid << 4;
    auto stageT = [&](int slot) {
      const char* gA = (const char*)bf8 + aBase + ((size_t)kt2 << 14);
      const char* gB = (const char*)tf8 + bOff;
      GLOAD16(gA + vo, &sA[slot][vo]);
      GLOAD16(gA + 8192 + vo, &sA[slot][8192 + vo]);
      GLOAD16(gB + vo, &sB[slot][vo]);
      GLOAD16(gB + 8192 + vo, &sB[slot][8192 + vo]);
      if (t2v < TT - 1) {
        ++t2v;
        bOff += 16384;
        kt2 = (kt2 == KTILES - 1) ? 0 : kt2 + 1;
      }
    };
    stageT(0);
    stageT(1);
    asm volatile("s_waitcnt vmcnt(0)" ::: "memory");
    __builtin_amdgcn_s_barrier();

    int qbc = 0;
    for (int j = 0; j < TT / 4; ++j) {       // 39 double-windows of 4 tiles
      bool firstA = ((j % 3) == 0);
      stageT(2);
      do_mfma(0, firstA);
      stageT(3);
      do_mfma(1, false);
      asm volatile("s_waitcnt vmcnt(0)" ::: "memory");
      __builtin_amdgcn_sched_barrier(0);
      __builtin_amdgcn_s_barrier();
      stageT(0);
      do_mfma(2, false);
      stageT(1);
      do_mfma(3, false);
      asm volatile("s_waitcnt vmcnt(0)" ::: "memory");
      __builtin_amdgcn_sched_barrier(0);
      __builtin_amdgcn_s_barrier();
      if (j % 3 == 2) {
        insert_pass();
        flushq(qbc);
        if (qbc + 1 < NQB) set_thr(qbc + 1);
        ++qbc;
      }
    }
  } else {
    int ktc = 0, qbc = 0;
    for (int t = 0; t < TT; ++t) {
      __syncthreads();
#pragma unroll
      for (int j = 0; j < 2; ++j) {
        int u = tid * 2 + j;
        int row = u >> 2, s = u & 3;
        const float* srcA = bank + (size_t)(b * 256 + row) * CC + ktc * 64 + s * 16;
        float4 f0 = *reinterpret_cast<const float4*>(srcA);
        float4 f1 = *reinterpret_cast<const float4*>(srcA + 4);
        float4 f2 = *reinterpret_cast<const float4*>(srcA + 8);
        float4 f3 = *reinterpret_cast<const float4*>(srcA + 12);
        *reinterpret_cast<i32x4v*>(&sA[0][row * 64 + swz4(s, row) * 16]) = pk16(f0, f1, f2, f3);
        int qr = qbc * 256 + row;
        qr = qr < NQ ? qr : NQ - 1;
        const float* srcB = tok + (size_t)qr * CC + ktc * 64 + s * 16;
        f0 = *reinterpret_cast<const float4*>(srcB);
        f1 = *reinterpret_cast<const float4*>(srcB + 4);
        f2 = *reinterpret_cast<const float4*>(srcB + 8);
        f3 = *reinterpret_cast<const float4*>(srcB + 12);
        *reinterpret_cast<i32x4v*>(&sB[0][row * 64 + swz4(s, row) * 16]) = pk16(f0, f1, f2, f3);
      }
      __syncthreads();
      do_mfma(0, ktc == 0);
      if (ktc == KTILES - 1) {
        __syncthreads();
        insert_pass();
        flushq(qbc);
        if (qbc + 1 < NQB) set_thr(qbc + 1);
        ktc = 0; ++qbc;
      } else {
        ++ktc;
      }
    }
  }
}

// ---------------- merge (r14 version): wave/query, top-16 + exact rescore ----
__global__ __launch_bounds__(256) void merge_rescore(
    const float* __restrict__ tok, const float* __restrict__ bank,
    const unsigned* __restrict__ cand, float* __restrict__ out) {
  int q = blockIdx.x * 4 + (threadIdx.x >> 6);
  int lane = threadIdx.x & 63;
  const unsigned* cp = cand + (size_t)q * 1280;
  unsigned e[20];
#pragma unroll
  for (int j = 0; j < 20; ++j) e[j] = cp[lane * 20 + j];
  unsigned gids[16];
#pragma unroll
  for (int r = 0; r < 16; ++r) {
    unsigned bv = e[0];
#pragma unroll
    for (int j = 1; j < 20; ++j) bv = e[j] < bv ? e[j] : bv;
    unsigned rv = bv;
    int rl = lane;
#pragma unroll
    for (int m = 32; m >= 1; m >>= 1) {
      unsigned ov = (unsigned)__shfl_xor((int)rv, m, 64);
      int ol = __shfl_xor(rl, m, 64);
      if (ov < rv || (ov == rv && ol < rl)) { rv = ov; rl = ol; }
    }
    unsigned gid = 0;
    if (lane == rl) {
      bool done = false;
#pragma unroll
      for (int j = 0; j < 20; ++j) {
        if (!done && e[j] == rv) {
          gid = (unsigned)((lane * 4 + j / 5) * 256) + (e[j] & 255u);
          e[j] = 0xFFFFFFFFu;
          done = true;
        }
      }
    }
    gids[r] = (unsigned)__shfl((int)gid, rl, 64);
  }
  float xv[12];
  {
    const float* xp = tok + (size_t)q * CC + lane * 12;
    float4 a = *reinterpret_cast<const float4*>(xp);
    float4 bq = *reinterpret_cast<const float4*>(xp + 4);
    float4 cc4 = *reinterpret_cast<const float4*>(xp + 8);
    xv[0] = a.x; xv[1] = a.y; xv[2] = a.z; xv[3] = a.w;
    xv[4] = bq.x; xv[5] = bq.y; xv[6] = bq.z; xv[7] = bq.w;
    xv[8] = cc4.x; xv[9] = cc4.y; xv[10] = cc4.z; xv[11] = cc4.w;
  }
  float d2e[16];
#pragma unroll
  for (int r = 0; r < 16; ++r) {
    const float* yp = bank + (size_t)(gids[r] & (MM - 1)) * CC + lane * 12;
    float4 a = *reinterpret_cast<const float4*>(yp);
    float4 bq = *reinterpret_cast<const float4*>(yp + 4);
    float4 cc4 = *reinterpret_cast<const float4*>(yp + 8);
    float yv[12];
    yv[0] = a.x; yv[1] = a.y; yv[2] = a.z; yv[3] = a.w;
    yv[4] = bq.x; yv[5] = bq.y; yv[6] = bq.z; yv[7] = bq.w;
    yv[8] = cc4.x; yv[9] = cc4.y; yv[10] = cc4.z; yv[11] = cc4.w;
    float s = 0.f;
#pragma unroll
    for (int e2 = 0; e2 < 12; ++e2) {
      float d = xv[e2] - yv[e2];
      s = fmaf(d, d, s);
    }
#pragma unroll
    for (int m = 32; m >= 1; m >>= 1) s += __shfl_xor(s, m, 64);
    d2e[r] = s;
  }
  float d1sq = 0.f, d5sq = 0.f;
#pragma unroll
  for (int r5 = 0; r5 < 5; ++r5) {
    float bv = d2e[0];
    int bj = 0;
#pragma unroll
    for (int j = 1; j < 16; ++j)
      if (d2e[j] < bv) { bv = d2e[j]; bj = j; }
    if (r5 == 0) d1sq = bv;
    if (r5 == 4) d5sq = bv;
#pragma unroll
    for (int j = 0; j < 16; ++j)
      if (j == bj) d2e[j] = 3.4e38f;
  }
  float d1 = sqrtf(fmaxf(d1sq, 0.f));
  float d5 = sqrtf(fmaxf(d5sq, 0.f));
  float gap = fmaxf(d5 - d1, 0.f);
  float sc = d1 * (1.f - expf(-gap));
  if (lane == 0) out[q] = sc;
}

extern "C" void kernel_launch(void* const* d_in, const int* in_sizes, int n_in,
                              void* d_out, int out_size, void* d_ws, size_t ws_size,
                              hipStream_t stream) {
  const float* tok = (const float*)d_in[0];   // 3136x768 fp32
  const float* bank = (const float*)d_in[1];  // 65536x768 fp32
  float* out = (float*)d_out;                 // 3136 fp32
  char* ws = (char*)d_ws;
  float* y2 = (float*)ws;                                     // 256KB
  float* x2 = (float*)(ws + 262144);                          // 13KB
  unsigned* cand = (unsigned*)(ws + 1048576);                 // 17.04MB
  unsigned char* bf8 = (unsigned char*)(ws + 18874368);       // 50.33MB (fp8 bank tiles)
  unsigned char* tf8 = (unsigned char*)(ws + 69206016);       // 2.56MB (fp8 tok tiles)
  const size_t WS_NEED = 71761920ull;

  if (ws_size >= WS_NEED) {
    convert_bank_y2<<<MM / 4, 256, 0, stream>>>(bank, bf8, y2);
    convert_tok_x2<<<QPAD / 4, 256, 0, stream>>>(tok, tf8, x2);
    gemm_topk<1><<<256, 512, 0, stream>>>(tok, bank, bf8, tf8, y2, x2, cand);
  } else {
    prep_sumsq<<<(MM + QPAD) / 4, 256, 0, stream>>>(tok, bank, y2, x2);
    gemm_topk<0><<<256, 512, 0, stream>>>(tok, bank, bf8, tf8, y2, x2, cand);
  }
  merge_rescore<<<NQ / 4, 256, 0, stream>>>(tok, bank, cand, out);
}